// Round 2
// baseline (1572.096 us; speedup 1.0000x reference)
//
#include <hip/hip_runtime.h>
#include <hip/hip_bf16.h>

// LINK forward: out[i, o] = b[o] + sum over edges (i -> j) of W[o, j]
// N=100000 nodes, OUT=64 channels, E=3200000 edges.
//
// R1 strategy: the exact-CSR scatter had 16x write amplification (197 MB for
// 12.8 MB of data, 220 us). Replace with coarse bucketing (128 rows/bucket)
// + fused per-bucket LDS accumulation:
//   transpose W -> WT[N][64]
//   bucket_count (per-WG LDS hist) -> scan -> bucket_scatter (packed row|col,
//   sequential frontier appends => ~1x write amp)
//   bucket_accum: 1 WG/bucket, 128x64 f32 acc in 32 KB LDS, wave reads 64
//   packed edges coalesced, shfl-broadcast, 4-unrolled WT column loads
//   (L3-resident), ds_add_f32 into LDS, coalesced store + bias.

#define OUTC 64
#define BROWS 128          // rows per bucket
#define NB_MAX 1024        // max buckets (N <= 131072)
#define CHUNK 8192         // edges per workgroup in count/scatter

// ---------------- transpose W[64][N] -> WT[N][64] ----------------
__global__ __launch_bounds__(256) void transpose_W(const float* __restrict__ W,
                                                   float* __restrict__ WT, int n) {
    __shared__ float tile[64][65];   // +1 pad
    const int n0   = blockIdx.x * 64;
    const int lane = threadIdx.x & 63;
    const int w    = threadIdx.x >> 6;   // 0..3
    #pragma unroll
    for (int k = 0; k < 16; ++k) {
        int o = w * 16 + k;
        int nn = n0 + lane;
        tile[o][lane] = (nn < n) ? W[(size_t)o * n + nn] : 0.f;
    }
    __syncthreads();
    #pragma unroll
    for (int k = 0; k < 16; ++k) {
        int nl = w * 16 + k;
        int nn = n0 + nl;
        if (nn < n) WT[(size_t)nn * OUTC + lane] = tile[lane][nl];
    }
}

// ---------------- per-WG LDS histogram -> global bucket counts ----------------
__global__ __launch_bounds__(256) void bucket_count(const int* __restrict__ rows,
                                                    int* __restrict__ bcnt,
                                                    int E, int NB) {
    __shared__ int hist[NB_MAX];
    for (int i = threadIdx.x; i < NB; i += 256) hist[i] = 0;
    __syncthreads();
    const int base = blockIdx.x * CHUNK;
    const int lim  = min(E, base + CHUNK);
    for (int e = base + threadIdx.x; e < lim; e += 256)
        atomicAdd(&hist[rows[e] >> 7], 1);
    __syncthreads();
    for (int i = threadIdx.x; i < NB; i += 256) {
        int c = hist[i];
        if (c) atomicAdd(&bcnt[i], c);
    }
}

// ---------------- exclusive scan of NB (<=1024) bucket counts, 1 block ----------------
__global__ __launch_bounds__(256) void scan_buckets(const int* __restrict__ bcnt,
                                                    int* __restrict__ offsets,
                                                    int* __restrict__ cursor,
                                                    int NB, int E) {
    __shared__ int lds[256];
    const int tid  = threadIdx.x;
    const int base = tid * 4;
    int v[4];
    int s = 0;
    #pragma unroll
    for (int k = 0; k < 4; ++k) {
        v[k] = (base + k < NB) ? bcnt[base + k] : 0;
        s += v[k];
    }
    lds[tid] = s;
    __syncthreads();
    for (int off = 1; off < 256; off <<= 1) {
        int t = 0;
        if (tid >= off) t = lds[tid - off];
        __syncthreads();
        if (tid >= off) lds[tid] += t;
        __syncthreads();
    }
    int ex = lds[tid] - s;
    #pragma unroll
    for (int k = 0; k < 4; ++k) {
        if (base + k < NB) { offsets[base + k] = ex; cursor[base + k] = ex; }
        ex += v[k];
    }
    if (tid == 0) offsets[NB] = E;
}

// ---------------- scatter packed (row&127)<<17 | col into bucket regions ----------------
__global__ __launch_bounds__(256) void bucket_scatter(const int* __restrict__ rows,
                                                      const int* __restrict__ cols,
                                                      int* __restrict__ cursor,
                                                      unsigned* __restrict__ packed,
                                                      int E, int NB) {
    __shared__ int hist[NB_MAX];
    for (int i = threadIdx.x; i < NB; i += 256) hist[i] = 0;
    __syncthreads();
    const int base = blockIdx.x * CHUNK;
    const int lim  = min(E, base + CHUNK);
    for (int e = base + threadIdx.x; e < lim; e += 256)
        atomicAdd(&hist[rows[e] >> 7], 1);
    __syncthreads();
    // reserve a contiguous global range per bucket; hist[b] becomes the cursor
    for (int i = threadIdx.x; i < NB; i += 256) {
        int c = hist[i];
        hist[i] = c ? atomicAdd(&cursor[i], c) : 0;
    }
    __syncthreads();
    for (int e = base + threadIdx.x; e < lim; e += 256) {
        int r = rows[e];
        int b = r >> 7;
        int pos = atomicAdd(&hist[b], 1);
        packed[pos] = ((unsigned)(r & 127) << 17) | (unsigned)cols[e];
    }
}

// ---------------- fused accumulate: 1 WG per bucket, 32 KB LDS acc ----------------
__global__ __launch_bounds__(256) void bucket_accum(const float* __restrict__ WT,
                                                    const unsigned* __restrict__ packed,
                                                    const int* __restrict__ offsets,
                                                    const float* __restrict__ bias,
                                                    float* __restrict__ out, int N) {
    __shared__ float acc[BROWS * OUTC];   // 32 KB
    const int b    = blockIdx.x;
    const int tid  = threadIdx.x;
    const int lane = tid & 63;
    const int w    = tid >> 6;
    for (int i = tid; i < BROWS * OUTC; i += 256) acc[i] = 0.f;
    __syncthreads();
    const int start = offsets[b];
    const int end   = offsets[b + 1];
    for (int eb = start + w * 64; eb < end; eb += 256) {
        int nv = end - eb;
        if (nv > 64) nv = 64;
        unsigned v = (lane < nv) ? packed[eb + lane] : 0u;
        int j = 0;
        for (; j + 3 < nv; j += 4) {
            unsigned u0 = __shfl(v, j + 0);
            unsigned u1 = __shfl(v, j + 1);
            unsigned u2 = __shfl(v, j + 2);
            unsigned u3 = __shfl(v, j + 3);
            float w0 = WT[(size_t)(u0 & 0x1FFFFu) * OUTC + lane];
            float w1 = WT[(size_t)(u1 & 0x1FFFFu) * OUTC + lane];
            float w2 = WT[(size_t)(u2 & 0x1FFFFu) * OUTC + lane];
            float w3 = WT[(size_t)(u3 & 0x1FFFFu) * OUTC + lane];
            __hip_atomic_fetch_add(&acc[(u0 >> 17) * OUTC + lane], w0,
                                   __ATOMIC_RELAXED, __HIP_MEMORY_SCOPE_WORKGROUP);
            __hip_atomic_fetch_add(&acc[(u1 >> 17) * OUTC + lane], w1,
                                   __ATOMIC_RELAXED, __HIP_MEMORY_SCOPE_WORKGROUP);
            __hip_atomic_fetch_add(&acc[(u2 >> 17) * OUTC + lane], w2,
                                   __ATOMIC_RELAXED, __HIP_MEMORY_SCOPE_WORKGROUP);
            __hip_atomic_fetch_add(&acc[(u3 >> 17) * OUTC + lane], w3,
                                   __ATOMIC_RELAXED, __HIP_MEMORY_SCOPE_WORKGROUP);
        }
        for (; j < nv; ++j) {
            unsigned u = __shfl(v, j);
            float wv = WT[(size_t)(u & 0x1FFFFu) * OUTC + lane];
            __hip_atomic_fetch_add(&acc[(u >> 17) * OUTC + lane], wv,
                                   __ATOMIC_RELAXED, __HIP_MEMORY_SCOPE_WORKGROUP);
        }
    }
    __syncthreads();
    const int node0 = b * BROWS;
    const int nrows = min(BROWS, N - node0);
    const float bb = bias[lane];
    for (int r = w; r < nrows; r += 4)
        out[(size_t)(node0 + r) * OUTC + lane] = acc[r * OUTC + lane] + bb;
}

extern "C" void kernel_launch(void* const* d_in, const int* in_sizes, int n_in,
                              void* d_out, int out_size, void* d_ws, size_t ws_size,
                              hipStream_t stream) {
    const int*   edges = (const int*)d_in[0];    // [2, E]: rows then cols
    const float* W     = (const float*)d_in[1];  // [64, N]
    const float* bias  = (const float*)d_in[2];  // [64]
    float*       out   = (float*)d_out;          // [N, 64]

    const int E  = in_sizes[0] / 2;
    const int N  = in_sizes[1] / OUTC;
    const int NB = (N + BROWS - 1) / BROWS;      // 782 for N=100000

    // workspace layout
    char* ws = (char*)d_ws;
    size_t off = 0;
    float* WT = (float*)(ws + off);        off += (size_t)N * OUTC * sizeof(float);
    off = (off + 255) & ~(size_t)255;
    int* offsets = (int*)(ws + off);       off += (size_t)(NB + 1) * sizeof(int);
    off = (off + 255) & ~(size_t)255;
    int* bcnt = (int*)(ws + off);          off += (size_t)NB * sizeof(int);
    off = (off + 255) & ~(size_t)255;
    int* cursor = (int*)(ws + off);        off += (size_t)NB * sizeof(int);
    off = (off + 255) & ~(size_t)255;
    unsigned* packed = (unsigned*)(ws + off); off += (size_t)E * sizeof(unsigned);
    (void)ws_size;

    const int* rows = edges;
    const int* cols = edges + E;

    hipMemsetAsync(bcnt, 0, (size_t)NB * sizeof(int), stream);

    transpose_W<<<(N + 63) / 64, 256, 0, stream>>>(W, WT, N);

    const int nchunks = (E + CHUNK - 1) / CHUNK;   // 391
    bucket_count<<<nchunks, 256, 0, stream>>>(rows, bcnt, E, NB);
    scan_buckets<<<1, 256, 0, stream>>>(bcnt, offsets, cursor, NB, E);
    bucket_scatter<<<nchunks, 256, 0, stream>>>(rows, cols, cursor, packed, E, NB);
    bucket_accum<<<NB, 256, 0, stream>>>(WT, packed, offsets, bias, out, N);
}

// Round 3
// 310.941 us; speedup vs baseline: 5.0559x; 5.0559x over previous
//
#include <hip/hip_runtime.h>
#include <hip/hip_bf16.h>

// LINK forward: out[i, o] = b[o] + sum over edges (i -> j) of W[o, j]
// N=100000, OUT=64, E=3200000.
//
// R3: two-phase radix to exact CSR (fixes R0's 197MB write amplification
// without R2's latency-bound LDS-atomic consumer):
//   1. transpose W -> WT[N][64]                       (~51 MB traffic)
//   2. bucket_count + scan: 782 buckets of 128 rows
//   3. bucket_scatter: packed (row&127)<<17|col appended at 782 sequential
//      frontiers -> ~1x write amplification (verified R2: not in top-5)
//   4. bucket_sort: 1 WG/bucket LDS counting sort -> exact per-node CSR;
//      random writes confined to a contiguous ~16KB window (L2-resident)
//   5. gather_node (R0's consumer, unroll 8): 1 wave/node, lane=channel,
//      register accumulation, no shfl, no LDS atomics.

#define OUTC 64
#define BROWS 128
#define NB_MAX 1024
#define CHUNK 8192

// ---------------- transpose W[64][N] -> WT[N][64] ----------------
__global__ __launch_bounds__(256) void transpose_W(const float* __restrict__ W,
                                                   float* __restrict__ WT, int n) {
    __shared__ float tile[64][65];
    const int n0   = blockIdx.x * 64;
    const int lane = threadIdx.x & 63;
    const int w    = threadIdx.x >> 6;
    #pragma unroll
    for (int k = 0; k < 16; ++k) {
        int o = w * 16 + k;
        int nn = n0 + lane;
        tile[o][lane] = (nn < n) ? W[(size_t)o * n + nn] : 0.f;
    }
    __syncthreads();
    #pragma unroll
    for (int k = 0; k < 16; ++k) {
        int nl = w * 16 + k;
        int nn = n0 + nl;
        if (nn < n) WT[(size_t)nn * OUTC + lane] = tile[lane][nl];
    }
}

// ---------------- per-WG LDS histogram -> global bucket counts ----------------
__global__ __launch_bounds__(256) void bucket_count(const int* __restrict__ rows,
                                                    int* __restrict__ bcnt,
                                                    int E, int NB) {
    __shared__ int hist[NB_MAX];
    for (int i = threadIdx.x; i < NB; i += 256) hist[i] = 0;
    __syncthreads();
    const int base = blockIdx.x * CHUNK;
    const int lim  = min(E, base + CHUNK);
    for (int e = base + threadIdx.x; e < lim; e += 256)
        atomicAdd(&hist[rows[e] >> 7], 1);
    __syncthreads();
    for (int i = threadIdx.x; i < NB; i += 256) {
        int c = hist[i];
        if (c) atomicAdd(&bcnt[i], c);
    }
}

// ---------------- exclusive scan of NB bucket counts, 1 block ----------------
__global__ __launch_bounds__(256) void scan_buckets(const int* __restrict__ bcnt,
                                                    int* __restrict__ offsets,
                                                    int* __restrict__ cursor,
                                                    int NB, int E) {
    __shared__ int lds[256];
    const int tid  = threadIdx.x;
    const int base = tid * 4;
    int v[4];
    int s = 0;
    #pragma unroll
    for (int k = 0; k < 4; ++k) {
        v[k] = (base + k < NB) ? bcnt[base + k] : 0;
        s += v[k];
    }
    lds[tid] = s;
    __syncthreads();
    for (int off = 1; off < 256; off <<= 1) {
        int t = 0;
        if (tid >= off) t = lds[tid - off];
        __syncthreads();
        if (tid >= off) lds[tid] += t;
        __syncthreads();
    }
    int ex = lds[tid] - s;
    #pragma unroll
    for (int k = 0; k < 4; ++k) {
        if (base + k < NB) { offsets[base + k] = ex; cursor[base + k] = ex; }
        ex += v[k];
    }
    if (tid == 0) offsets[NB] = E;
}

// ---------------- scatter packed (row&127)<<17 | col into bucket regions ----------------
__global__ __launch_bounds__(256) void bucket_scatter(const int* __restrict__ rows,
                                                      const int* __restrict__ cols,
                                                      int* __restrict__ cursor,
                                                      unsigned* __restrict__ packed,
                                                      int E, int NB) {
    __shared__ int hist[NB_MAX];
    for (int i = threadIdx.x; i < NB; i += 256) hist[i] = 0;
    __syncthreads();
    const int base = blockIdx.x * CHUNK;
    const int lim  = min(E, base + CHUNK);
    for (int e = base + threadIdx.x; e < lim; e += 256)
        atomicAdd(&hist[rows[e] >> 7], 1);
    __syncthreads();
    for (int i = threadIdx.x; i < NB; i += 256) {
        int c = hist[i];
        hist[i] = c ? atomicAdd(&cursor[i], c) : 0;
    }
    __syncthreads();
    for (int e = base + threadIdx.x; e < lim; e += 256) {
        int r = rows[e];
        int b = r >> 7;
        int pos = atomicAdd(&hist[b], 1);
        packed[pos] = ((unsigned)(r & 127) << 17) | (unsigned)cols[e];
    }
}

// ---------------- per-bucket LDS counting sort -> exact per-node CSR ----------------
__global__ __launch_bounds__(256) void bucket_sort(const unsigned* __restrict__ packed,
                                                   const int* __restrict__ offsets,
                                                   int* __restrict__ node_off,
                                                   int* __restrict__ sorted_col,
                                                   int N, int E) {
    __shared__ int cnt[BROWS];
    __shared__ int cur[BROWS];
    const int b     = blockIdx.x;
    const int tid   = threadIdx.x;
    const int start = offsets[b];
    const int end   = offsets[b + 1];
    if (tid < BROWS) cnt[tid] = 0;
    __syncthreads();
    // pass 1: count per-node within bucket
    for (int e = start + tid; e < end; e += 256)
        atomicAdd(&cnt[packed[e] >> 17], 1);
    __syncthreads();
    // inclusive Hillis-Steele scan over 128 counters (threads 0..127)
    int v = (tid < BROWS) ? cnt[tid] : 0;
    for (int off = 1; off < BROWS; off <<= 1) {
        int t = 0;
        if (tid < BROWS && tid >= off) t = cnt[tid - off];
        __syncthreads();
        if (tid < BROWS && tid >= off) cnt[tid] += t;
        __syncthreads();
    }
    if (tid < BROWS) {
        int ex = cnt[tid] - v;          // exclusive prefix within bucket
        cur[tid] = ex;
        int node = b * BROWS + tid;
        if (node < N) node_off[node] = start + ex;
    }
    if (b == 0 && tid == 0) node_off[N] = E;
    __syncthreads();
    // pass 2: scatter cols into CSR order (writes confined to [start,end))
    for (int e = start + tid; e < end; e += 256) {
        unsigned u = packed[e];
        int r = u >> 17;
        int pos = atomicAdd(&cur[r], 1);
        sorted_col[start + pos] = (int)(u & 0x1FFFFu);
    }
}

// ---------------- gather: one wave per node, lane = channel ----------------
__global__ __launch_bounds__(256) void gather_node(const float* __restrict__ WT,
                                                   const int* __restrict__ sorted_col,
                                                   const int* __restrict__ node_off,
                                                   const float* __restrict__ bias,
                                                   float* __restrict__ out, int N) {
    const int wave = (blockIdx.x * blockDim.x + threadIdx.x) >> 6;
    const int lane = threadIdx.x & 63;
    if (wave >= N) return;
    const int start = node_off[wave];
    const int end   = node_off[wave + 1];
    float a0 = bias[lane], a1 = 0.f, a2 = 0.f, a3 = 0.f;
    float a4 = 0.f, a5 = 0.f, a6 = 0.f, a7 = 0.f;
    int e = start;
    for (; e + 7 < end; e += 8) {
        int c0 = sorted_col[e + 0];
        int c1 = sorted_col[e + 1];
        int c2 = sorted_col[e + 2];
        int c3 = sorted_col[e + 3];
        int c4 = sorted_col[e + 4];
        int c5 = sorted_col[e + 5];
        int c6 = sorted_col[e + 6];
        int c7 = sorted_col[e + 7];
        a0 += WT[(size_t)c0 * OUTC + lane];
        a1 += WT[(size_t)c1 * OUTC + lane];
        a2 += WT[(size_t)c2 * OUTC + lane];
        a3 += WT[(size_t)c3 * OUTC + lane];
        a4 += WT[(size_t)c4 * OUTC + lane];
        a5 += WT[(size_t)c5 * OUTC + lane];
        a6 += WT[(size_t)c6 * OUTC + lane];
        a7 += WT[(size_t)c7 * OUTC + lane];
    }
    for (; e + 3 < end; e += 4) {
        int c0 = sorted_col[e + 0];
        int c1 = sorted_col[e + 1];
        int c2 = sorted_col[e + 2];
        int c3 = sorted_col[e + 3];
        a0 += WT[(size_t)c0 * OUTC + lane];
        a1 += WT[(size_t)c1 * OUTC + lane];
        a2 += WT[(size_t)c2 * OUTC + lane];
        a3 += WT[(size_t)c3 * OUTC + lane];
    }
    for (; e < end; ++e) a0 += WT[(size_t)sorted_col[e] * OUTC + lane];
    out[(size_t)wave * OUTC + lane] = ((a0 + a1) + (a2 + a3)) + ((a4 + a5) + (a6 + a7));
}

extern "C" void kernel_launch(void* const* d_in, const int* in_sizes, int n_in,
                              void* d_out, int out_size, void* d_ws, size_t ws_size,
                              hipStream_t stream) {
    const int*   edges = (const int*)d_in[0];    // [2, E]: rows then cols
    const float* W     = (const float*)d_in[1];  // [64, N]
    const float* bias  = (const float*)d_in[2];  // [64]
    float*       out   = (float*)d_out;          // [N, 64]

    const int E  = in_sizes[0] / 2;
    const int N  = in_sizes[1] / OUTC;
    const int NB = (N + BROWS - 1) / BROWS;      // 782 for N=100000

    // workspace layout
    char* ws = (char*)d_ws;
    size_t off = 0;
    float* WT = (float*)(ws + off);        off += (size_t)N * OUTC * sizeof(float);
    off = (off + 255) & ~(size_t)255;
    int* offsets = (int*)(ws + off);       off += (size_t)(NB + 1) * sizeof(int);
    off = (off + 255) & ~(size_t)255;
    int* bcnt = (int*)(ws + off);          off += (size_t)NB * sizeof(int);
    off = (off + 255) & ~(size_t)255;
    int* cursor = (int*)(ws + off);        off += (size_t)NB * sizeof(int);
    off = (off + 255) & ~(size_t)255;
    int* node_off = (int*)(ws + off);      off += (size_t)(N + 1) * sizeof(int);
    off = (off + 255) & ~(size_t)255;
    unsigned* packed = (unsigned*)(ws + off); off += (size_t)E * sizeof(unsigned);
    off = (off + 255) & ~(size_t)255;
    int* sorted_col = (int*)(ws + off);    off += (size_t)E * sizeof(int);
    (void)ws_size;

    const int* rows = edges;
    const int* cols = edges + E;

    hipMemsetAsync(bcnt, 0, (size_t)NB * sizeof(int), stream);

    transpose_W<<<(N + 63) / 64, 256, 0, stream>>>(W, WT, N);

    const int nchunks = (E + CHUNK - 1) / CHUNK;   // 391
    bucket_count<<<nchunks, 256, 0, stream>>>(rows, bcnt, E, NB);
    scan_buckets<<<1, 256, 0, stream>>>(bcnt, offsets, cursor, NB, E);
    bucket_scatter<<<nchunks, 256, 0, stream>>>(rows, cols, cursor, packed, E, NB);
    bucket_sort<<<NB, 256, 0, stream>>>(packed, offsets, node_off, sorted_col, N, E);
    gather_node<<<(N + 3) / 4, 256, 0, stream>>>(WT, sorted_col, node_off, bias, out, N);
}

// Round 4
// 307.848 us; speedup vs baseline: 5.1067x; 1.0100x over previous
//
#include <hip/hip_runtime.h>
#include <hip/hip_bf16.h>

// LINK forward: out[i, o] = b[o] + sum over edges (i -> j) of W[o, j]
// N=100000, OUT=64, E=3200000.
//
// R4: (a) kill the ~175us setup chain: no global atomics anywhere -- per-chunk
// count matrix hist[c][b] + one scan kernel yields exact per-(chunk,bucket)
// scatter bases; rows/cols read exactly once in scatter; bucket_sort fused
// into the gather kernel (sort to LDS, gather directly). No memsets.
// (b) halve gather L2-miss traffic: WT stored as packed bf16 (column=128B).
// Gather: half-wave per edge (lane loads uint = 2 channels), f32 accum,
// __shfl_xor(32) combine, float2 coalesced store. Error budget: 65 * 6e-6
// + 1.2e-4 ordering ~ 5e-4 << 1.19e-3 threshold.

#define OUTC 64
#define BROWS 128          // rows per bucket
#define NB_MAX 1024
#define CHUNK 8192         // edges per chunk WG
#define CAP 5120           // per-bucket LDS col capacity (mean 4096, sigma 64)

__device__ inline unsigned f2bf(float x) {           // RNE f32 -> bf16 bits
    unsigned u = __float_as_uint(x);
    return (u + 0x7FFFu + ((u >> 16) & 1u)) >> 16;
}
__device__ inline float bf_lo(unsigned u) { return __uint_as_float(u << 16); }
__device__ inline float bf_hi(unsigned u) { return __uint_as_float(u & 0xFFFF0000u); }

// ---------------- A: transpose W[64][N] -> WTh[N][32] packed bf16x2 ----------------
__global__ __launch_bounds__(256) void transpose_cast(const float* __restrict__ W,
                                                      unsigned* __restrict__ WTh, int n) {
    __shared__ float tile[64][65];
    const int n0   = blockIdx.x * 64;
    const int lane = threadIdx.x & 63;
    const int wv   = threadIdx.x >> 6;
    #pragma unroll
    for (int k = 0; k < 16; ++k) {
        int o  = wv * 16 + k;
        int nn = n0 + lane;
        tile[o][lane] = (nn < n) ? W[(size_t)o * n + nn] : 0.f;
    }
    __syncthreads();
    const int u   = threadIdx.x & 31;      // uint index = channels 2u, 2u+1
    const int nbs = threadIdx.x >> 5;      // 0..7
    #pragma unroll
    for (int k = 0; k < 8; ++k) {
        int nl = nbs + 8 * k;
        int nn = n0 + nl;
        if (nn < n)
            WTh[(size_t)nn * 32 + u] = f2bf(tile[2 * u][nl]) | (f2bf(tile[2 * u + 1][nl]) << 16);
    }
}

// ---------------- B: per-chunk bucket histogram (no global atomics) ----------------
__global__ __launch_bounds__(256) void count_chunks(const int* __restrict__ rows,
                                                    int* __restrict__ hist,
                                                    int E, int NB) {
    __shared__ int h[NB_MAX];
    for (int i = threadIdx.x; i < NB; i += 256) h[i] = 0;
    __syncthreads();
    const int base = blockIdx.x * CHUNK;
    const int lim  = min(E, base + CHUNK);
    for (int e = base + threadIdx.x; e < lim; e += 256)
        atomicAdd(&h[rows[e] >> 7], 1);
    __syncthreads();
    int* dst = hist + (size_t)blockIdx.x * NB;
    for (int i = threadIdx.x; i < NB; i += 256) dst[i] = h[i];
}

// ---------------- C: per-bucket scan over chunks + bucket base scan ----------------
__global__ __launch_bounds__(1024) void scan_offsets(const int* __restrict__ hist,
                                                     int* __restrict__ cb,
                                                     int* __restrict__ base_g,
                                                     int NB, int nchunks, int E) {
    __shared__ int tot[1024];
    const int b = threadIdx.x;
    int run = 0;
    if (b < NB) {
        int c = 0;
        for (; c + 7 < nchunks; c += 8) {
            int v[8];
            #pragma unroll
            for (int k = 0; k < 8; ++k) v[k] = hist[(size_t)(c + k) * NB + b];
            #pragma unroll
            for (int k = 0; k < 8; ++k) { cb[(size_t)(c + k) * NB + b] = run; run += v[k]; }
        }
        for (; c < nchunks; ++c) {
            int v = hist[(size_t)c * NB + b];
            cb[(size_t)c * NB + b] = run;
            run += v;
        }
    }
    tot[b] = (b < NB) ? run : 0;
    __syncthreads();
    for (int off = 1; off < 1024; off <<= 1) {
        int t = 0;
        if (b >= off) t = tot[b - off];
        __syncthreads();
        if (b >= off) tot[b] += t;
        __syncthreads();
    }
    if (b < NB) base_g[b] = tot[b] - run;   // exclusive bucket base
    if (b == NB - 1) base_g[NB] = tot[b];   // == E
}

// ---------------- D: single-pass scatter via precomputed bases ----------------
__global__ __launch_bounds__(256) void scatter_chunks(const int* __restrict__ rows,
                                                      const int* __restrict__ cols,
                                                      const int* __restrict__ cb,
                                                      const int* __restrict__ base_g,
                                                      unsigned* __restrict__ packed,
                                                      int E, int NB) {
    __shared__ int cur[NB_MAX];
    const int c = blockIdx.x;
    const int* mycb = cb + (size_t)c * NB;
    for (int i = threadIdx.x; i < NB; i += 256) cur[i] = mycb[i] + base_g[i];
    __syncthreads();
    const int base = c * CHUNK;
    const int lim  = min(E, base + CHUNK);
    for (int e = base + threadIdx.x; e < lim; e += 256) {
        int r = rows[e];
        int p = atomicAdd(&cur[r >> 7], 1);
        packed[p] = ((unsigned)(r & 127) << 17) | (unsigned)cols[e];
    }
}

// ---------------- E: fused per-bucket LDS counting sort + gather ----------------
__global__ __launch_bounds__(256) void sort_gather(const unsigned* __restrict__ WTh,
                                                   const unsigned* __restrict__ packed,
                                                   const int* __restrict__ base_g,
                                                   const float* __restrict__ bias,
                                                   float* __restrict__ out, int N) {
    __shared__ unsigned scol[CAP];            // 20 KB
    __shared__ int cnt[BROWS], off0[BROWS], tend[BROWS], cur[BROWS];
    __shared__ int ovf_n;
    __shared__ unsigned ovf[128];
    const int b    = blockIdx.x;
    const int tid  = threadIdx.x;
    const int lane = tid & 63;
    const int w    = tid >> 6;
    const int start = base_g[b];
    const int size  = base_g[b + 1] - start;
    if (tid < BROWS) cnt[tid] = 0;
    if (tid == 0) ovf_n = 0;
    __syncthreads();
    // count per node
    for (int e = tid; e < size; e += 256)
        atomicAdd(&cnt[packed[start + e] >> 17], 1);
    __syncthreads();
    // scan 128 counters
    int v = (tid < BROWS) ? cnt[tid] : 0;
    for (int off = 1; off < BROWS; off <<= 1) {
        int t = 0;
        if (tid < BROWS && tid >= off) t = cnt[tid - off];
        __syncthreads();
        if (tid < BROWS && tid >= off) cnt[tid] += t;
        __syncthreads();
    }
    if (tid < BROWS) { tend[tid] = cnt[tid]; off0[tid] = cnt[tid] - v; cur[tid] = cnt[tid] - v; }
    __syncthreads();
    // scatter cols into LDS (bucket-relative positions)
    for (int e = tid; e < size; e += 256) {
        unsigned u = packed[start + e];
        int p = atomicAdd(&cur[u >> 17], 1);
        if (p < CAP) scol[p] = u & 0x1FFFFu;
        else { int oi = atomicAdd(&ovf_n, 1); if (oi < 128) ovf[oi] = u; }
    }
    __syncthreads();
    // gather: wave w handles nodes r = w, w+4, ...; half-wave per edge parity
    const int hl   = lane & 31;
    const int half = lane >> 5;
    const float bx = bias[2 * hl];
    const float by = bias[2 * hl + 1];
    for (int r = w; r < BROWS; r += 4) {
        const int n = b * BROWS + r;
        if (n >= N) break;
        int s = off0[r], t = tend[r];
        if (s > CAP) s = CAP;
        if (t > CAP) t = CAP;
        float ax = 0.f, ay = 0.f;
        int e = s + half;
        for (; e + 14 < t; e += 16) {
            unsigned c0 = scol[e + 0],  c1 = scol[e + 2],  c2 = scol[e + 4],  c3 = scol[e + 6];
            unsigned c4 = scol[e + 8],  c5 = scol[e + 10], c6 = scol[e + 12], c7 = scol[e + 14];
            unsigned u0 = WTh[(size_t)c0 * 32 + hl];
            unsigned u1 = WTh[(size_t)c1 * 32 + hl];
            unsigned u2 = WTh[(size_t)c2 * 32 + hl];
            unsigned u3 = WTh[(size_t)c3 * 32 + hl];
            unsigned u4 = WTh[(size_t)c4 * 32 + hl];
            unsigned u5 = WTh[(size_t)c5 * 32 + hl];
            unsigned u6 = WTh[(size_t)c6 * 32 + hl];
            unsigned u7 = WTh[(size_t)c7 * 32 + hl];
            ax += bf_lo(u0); ay += bf_hi(u0);
            ax += bf_lo(u1); ay += bf_hi(u1);
            ax += bf_lo(u2); ay += bf_hi(u2);
            ax += bf_lo(u3); ay += bf_hi(u3);
            ax += bf_lo(u4); ay += bf_hi(u4);
            ax += bf_lo(u5); ay += bf_hi(u5);
            ax += bf_lo(u6); ay += bf_hi(u6);
            ax += bf_lo(u7); ay += bf_hi(u7);
        }
        for (; e < t; e += 2) {
            unsigned u = WTh[(size_t)scol[e] * 32 + hl];
            ax += bf_lo(u); ay += bf_hi(u);
        }
        ax += __shfl_xor(ax, 32);
        ay += __shfl_xor(ay, 32);
        if (half == 0) {
            float2 o;
            o.x = ax + bx;
            o.y = ay + by;
            ((float2*)out)[(size_t)n * 32 + hl] = o;
        }
    }
    __syncthreads();
    // overflow slow path (statistically never: CAP is mean+16 sigma)
    int no = ovf_n;
    if (no > 0) {
        if (no > 128) no = 128;
        for (int i = w; i < no; i += 4) {
            unsigned u = ovf[i];
            int n = b * BROWS + (int)(u >> 17);
            if (n < N && half == 0) {
                unsigned uu = WTh[(size_t)(u & 0x1FFFFu) * 32 + hl];
                atomicAdd(&out[(size_t)n * 64 + 2 * hl],     bf_lo(uu));
                atomicAdd(&out[(size_t)n * 64 + 2 * hl + 1], bf_hi(uu));
            }
        }
    }
}

extern "C" void kernel_launch(void* const* d_in, const int* in_sizes, int n_in,
                              void* d_out, int out_size, void* d_ws, size_t ws_size,
                              hipStream_t stream) {
    const int*   edges = (const int*)d_in[0];    // [2, E]: rows then cols
    const float* W     = (const float*)d_in[1];  // [64, N]
    const float* bias  = (const float*)d_in[2];  // [64]
    float*       out   = (float*)d_out;          // [N, 64]

    const int E       = in_sizes[0] / 2;
    const int N       = in_sizes[1] / OUTC;
    const int NB      = (N + BROWS - 1) / BROWS;       // 782
    const int nchunks = (E + CHUNK - 1) / CHUNK;       // 391

    // workspace layout
    char* ws = (char*)d_ws;
    size_t off = 0;
    unsigned* WTh = (unsigned*)(ws + off); off += (size_t)N * 32 * sizeof(unsigned);
    off = (off + 255) & ~(size_t)255;
    int* hist = (int*)(ws + off);          off += (size_t)nchunks * NB * sizeof(int);
    off = (off + 255) & ~(size_t)255;
    int* cb = (int*)(ws + off);            off += (size_t)nchunks * NB * sizeof(int);
    off = (off + 255) & ~(size_t)255;
    int* base_g = (int*)(ws + off);        off += (size_t)(NB + 1) * sizeof(int);
    off = (off + 255) & ~(size_t)255;
    unsigned* packed = (unsigned*)(ws + off); off += (size_t)E * sizeof(unsigned);
    (void)ws_size;

    const int* rows = edges;
    const int* cols = edges + E;

    transpose_cast<<<(N + 63) / 64, 256, 0, stream>>>(W, WTh, N);
    count_chunks<<<nchunks, 256, 0, stream>>>(rows, hist, E, NB);
    scan_offsets<<<1, 1024, 0, stream>>>(hist, cb, base_g, NB, nchunks, E);
    scatter_chunks<<<nchunks, 256, 0, stream>>>(rows, cols, cb, base_g, packed, E, NB);
    sort_gather<<<NB, 256, 0, stream>>>(WTh, packed, base_g, bias, out, N);
}

// Round 5
// 218.870 us; speedup vs baseline: 7.1828x; 1.4065x over previous
//
#include <hip/hip_runtime.h>
#include <hip/hip_bf16.h>

// LINK forward: out[i, o] = b[o] + sum over edges (i -> j) of W[o, j]
// N=100000, OUT=64, E=3200000.
//
// R5: the R4 pipeline was parallelism-starved, not bandwidth-starved
// (gather: 782 blocks = 3/CU, occupancy 30%; count/scatter: 391 blocks;
// scan: ONE block on one CU ~40us). Changes:
//  - BROWS 128->64: gather grid 1563 blocks (6.1/CU)
//  - CHUNK 8192->4096: count/scatter 782 blocks, int4 edge loads
//  - hierarchical 3-kernel scan (175 + 7 + 1 blocks) replaces 1-block scan
// Gather consumer unchanged (bf16-packed WT, half-wave/edge, f32 accum).

#define OUTC 64
#define BROWS 64           // rows per bucket
#define NB_MAX 2048
#define CHUNK 4096         // edges per chunk WG
#define GRP 32             // chunks per scan group
#define CAP 2560           // per-bucket LDS col capacity (mean 2048, sigma 45)

__device__ inline unsigned f2bf(float x) {           // RNE f32 -> bf16 bits
    unsigned u = __float_as_uint(x);
    return (u + 0x7FFFu + ((u >> 16) & 1u)) >> 16;
}
__device__ inline float bf_lo(unsigned u) { return __uint_as_float(u << 16); }
__device__ inline float bf_hi(unsigned u) { return __uint_as_float(u & 0xFFFF0000u); }

// ---------------- A: transpose W[64][N] -> WTh[N][32] packed bf16x2 ----------------
__global__ __launch_bounds__(256) void transpose_cast(const float* __restrict__ W,
                                                      unsigned* __restrict__ WTh, int n) {
    __shared__ float tile[64][65];
    const int n0   = blockIdx.x * 64;
    const int lane = threadIdx.x & 63;
    const int wv   = threadIdx.x >> 6;
    #pragma unroll
    for (int k = 0; k < 16; ++k) {
        int o  = wv * 16 + k;
        int nn = n0 + lane;
        tile[o][lane] = (nn < n) ? W[(size_t)o * n + nn] : 0.f;
    }
    __syncthreads();
    const int u   = threadIdx.x & 31;      // uint index = channels 2u, 2u+1
    const int nbs = threadIdx.x >> 5;      // 0..7
    #pragma unroll
    for (int k = 0; k < 8; ++k) {
        int nl = nbs + 8 * k;
        int nn = n0 + nl;
        if (nn < n)
            WTh[(size_t)nn * 32 + u] = f2bf(tile[2 * u][nl]) | (f2bf(tile[2 * u + 1][nl]) << 16);
    }
}

// ---------------- B: per-chunk bucket histogram (int4 loads) ----------------
__global__ __launch_bounds__(256) void count_chunks(const int* __restrict__ rows,
                                                    int* __restrict__ hist,
                                                    int E, int NB) {
    __shared__ int h[NB_MAX];
    const int tid = threadIdx.x;
    for (int i = tid; i < NB; i += 256) h[i] = 0;
    __syncthreads();
    const int base = blockIdx.x * CHUNK;
    const int lim  = min(E, base + CHUNK);
    #pragma unroll
    for (int it = 0; it < CHUNK / 1024; ++it) {
        int e = base + it * 1024 + tid * 4;
        if (e + 3 < lim) {
            int4 r = *(const int4*)(rows + e);
            atomicAdd(&h[r.x >> 6], 1);
            atomicAdd(&h[r.y >> 6], 1);
            atomicAdd(&h[r.z >> 6], 1);
            atomicAdd(&h[r.w >> 6], 1);
        } else {
            for (int j = 0; j < 4; ++j)
                if (e + j < lim) atomicAdd(&h[rows[e + j] >> 6], 1);
        }
    }
    __syncthreads();
    int* dst = hist + (size_t)blockIdx.x * NB;
    for (int i = tid; i < NB; i += 256) dst[i] = h[i];
}

// ---------------- C1: per-bucket scan within 32-chunk groups ----------------
__global__ __launch_bounds__(256) void scan_part(const int* __restrict__ hist,
                                                 int* __restrict__ cb,
                                                 int* __restrict__ gt,
                                                 int NB, int nchunks) {
    const int g = blockIdx.x;
    const int b = blockIdx.y * 256 + threadIdx.x;
    if (b >= NB) return;
    const int c0 = g * GRP;
    const int c1 = min(nchunks, c0 + GRP);
    int run = 0;
    for (int c = c0; c < c1; ++c) {
        int v = hist[(size_t)c * NB + b];
        cb[(size_t)c * NB + b] = run;
        run += v;
    }
    gt[(size_t)g * NB + b] = run;
}

// ---------------- C2: scan group totals per bucket (in place) ----------------
__global__ __launch_bounds__(256) void scan_grp(int* __restrict__ gt,
                                                int* __restrict__ tot,
                                                int NB, int ngroups) {
    const int b = blockIdx.x * 256 + threadIdx.x;
    if (b >= NB) return;
    int run = 0;
    for (int g = 0; g < ngroups; ++g) {
        int v = gt[(size_t)g * NB + b];
        gt[(size_t)g * NB + b] = run;
        run += v;
    }
    tot[b] = run;
}

// ---------------- C3: exclusive scan of bucket totals (in place, 1 block) ----------------
__global__ __launch_bounds__(512) void scan_base(int* __restrict__ base_g,
                                                 int NB, int E) {
    __shared__ int lds[512];
    const int tid  = threadIdx.x;
    const int base = tid * 4;
    int v[4];
    int s = 0;
    #pragma unroll
    for (int k = 0; k < 4; ++k) {
        v[k] = (base + k < NB) ? base_g[base + k] : 0;
        s += v[k];
    }
    lds[tid] = s;
    __syncthreads();
    for (int off = 1; off < 512; off <<= 1) {
        int t = 0;
        if (tid >= off) t = lds[tid - off];
        __syncthreads();
        if (tid >= off) lds[tid] += t;
        __syncthreads();
    }
    int ex = lds[tid] - s;
    #pragma unroll
    for (int k = 0; k < 4; ++k) {
        if (base + k < NB) base_g[base + k] = ex;
        ex += v[k];
    }
    if (tid == 0) base_g[NB] = E;
}

// ---------------- D: scatter via precomputed bases (int4 loads) ----------------
__global__ __launch_bounds__(256) void scatter_chunks(const int* __restrict__ rows,
                                                      const int* __restrict__ cols,
                                                      const int* __restrict__ cb,
                                                      const int* __restrict__ gt,
                                                      const int* __restrict__ base_g,
                                                      unsigned* __restrict__ packed,
                                                      int E, int NB) {
    __shared__ int cur[NB_MAX];
    const int c   = blockIdx.x;
    const int g   = c / GRP;
    const int tid = threadIdx.x;
    const int* mycb = cb + (size_t)c * NB;
    const int* mygt = gt + (size_t)g * NB;
    for (int i = tid; i < NB; i += 256) cur[i] = base_g[i] + mygt[i] + mycb[i];
    __syncthreads();
    const int base = c * CHUNK;
    const int lim  = min(E, base + CHUNK);
    #pragma unroll
    for (int it = 0; it < CHUNK / 1024; ++it) {
        int e = base + it * 1024 + tid * 4;
        if (e + 3 < lim) {
            int4 r = *(const int4*)(rows + e);
            int4 cc = *(const int4*)(cols + e);
            int p0 = atomicAdd(&cur[r.x >> 6], 1);
            int p1 = atomicAdd(&cur[r.y >> 6], 1);
            int p2 = atomicAdd(&cur[r.z >> 6], 1);
            int p3 = atomicAdd(&cur[r.w >> 6], 1);
            packed[p0] = ((unsigned)(r.x & 63) << 17) | (unsigned)cc.x;
            packed[p1] = ((unsigned)(r.y & 63) << 17) | (unsigned)cc.y;
            packed[p2] = ((unsigned)(r.z & 63) << 17) | (unsigned)cc.z;
            packed[p3] = ((unsigned)(r.w & 63) << 17) | (unsigned)cc.w;
        } else {
            for (int j = 0; j < 4; ++j) {
                if (e + j < lim) {
                    int r = rows[e + j];
                    int p = atomicAdd(&cur[r >> 6], 1);
                    packed[p] = ((unsigned)(r & 63) << 17) | (unsigned)cols[e + j];
                }
            }
        }
    }
}

// ---------------- E: fused per-bucket LDS counting sort + gather ----------------
__global__ __launch_bounds__(256) void sort_gather(const unsigned* __restrict__ WTh,
                                                   const unsigned* __restrict__ packed,
                                                   const int* __restrict__ base_g,
                                                   const float* __restrict__ bias,
                                                   float* __restrict__ out, int N) {
    __shared__ unsigned scol[CAP];            // 10 KB
    __shared__ int cnt[BROWS], off0[BROWS], tend[BROWS], cur[BROWS];
    __shared__ int ovf_n;
    __shared__ unsigned ovf[128];
    const int b    = blockIdx.x;
    const int tid  = threadIdx.x;
    const int lane = tid & 63;
    const int w    = tid >> 6;
    const int start = base_g[b];
    const int size  = base_g[b + 1] - start;
    if (tid < BROWS) cnt[tid] = 0;
    if (tid == 0) ovf_n = 0;
    __syncthreads();
    // count per node
    for (int e = tid; e < size; e += 256)
        atomicAdd(&cnt[packed[start + e] >> 17], 1);
    __syncthreads();
    // scan 64 counters (threads 0..63)
    int v = (tid < BROWS) ? cnt[tid] : 0;
    for (int off = 1; off < BROWS; off <<= 1) {
        int t = 0;
        if (tid < BROWS && tid >= off) t = cnt[tid - off];
        __syncthreads();
        if (tid < BROWS && tid >= off) cnt[tid] += t;
        __syncthreads();
    }
    if (tid < BROWS) { tend[tid] = cnt[tid]; off0[tid] = cnt[tid] - v; cur[tid] = cnt[tid] - v; }
    __syncthreads();
    // scatter cols into LDS (bucket-relative positions)
    for (int e = tid; e < size; e += 256) {
        unsigned u = packed[start + e];
        int p = atomicAdd(&cur[u >> 17], 1);
        if (p < CAP) scol[p] = u & 0x1FFFFu;
        else { int oi = atomicAdd(&ovf_n, 1); if (oi < 128) ovf[oi] = u; }
    }
    __syncthreads();
    // gather: wave w handles nodes r = w, w+4, ...; half-wave per edge parity
    const int hl   = lane & 31;
    const int half = lane >> 5;
    const float bx = bias[2 * hl];
    const float by = bias[2 * hl + 1];
    for (int r = w; r < BROWS; r += 4) {
        const int n = b * BROWS + r;
        if (n >= N) break;
        int s = off0[r], t = tend[r];
        if (s > CAP) s = CAP;
        if (t > CAP) t = CAP;
        float ax = 0.f, ay = 0.f;
        int e = s + half;
        for (; e + 14 < t; e += 16) {
            unsigned c0 = scol[e + 0],  c1 = scol[e + 2],  c2 = scol[e + 4],  c3 = scol[e + 6];
            unsigned c4 = scol[e + 8],  c5 = scol[e + 10], c6 = scol[e + 12], c7 = scol[e + 14];
            unsigned u0 = WTh[(size_t)c0 * 32 + hl];
            unsigned u1 = WTh[(size_t)c1 * 32 + hl];
            unsigned u2 = WTh[(size_t)c2 * 32 + hl];
            unsigned u3 = WTh[(size_t)c3 * 32 + hl];
            unsigned u4 = WTh[(size_t)c4 * 32 + hl];
            unsigned u5 = WTh[(size_t)c5 * 32 + hl];
            unsigned u6 = WTh[(size_t)c6 * 32 + hl];
            unsigned u7 = WTh[(size_t)c7 * 32 + hl];
            ax += bf_lo(u0); ay += bf_hi(u0);
            ax += bf_lo(u1); ay += bf_hi(u1);
            ax += bf_lo(u2); ay += bf_hi(u2);
            ax += bf_lo(u3); ay += bf_hi(u3);
            ax += bf_lo(u4); ay += bf_hi(u4);
            ax += bf_lo(u5); ay += bf_hi(u5);
            ax += bf_lo(u6); ay += bf_hi(u6);
            ax += bf_lo(u7); ay += bf_hi(u7);
        }
        for (; e < t; e += 2) {
            unsigned u = WTh[(size_t)scol[e] * 32 + hl];
            ax += bf_lo(u); ay += bf_hi(u);
        }
        ax += __shfl_xor(ax, 32);
        ay += __shfl_xor(ay, 32);
        if (half == 0) {
            float2 o;
            o.x = ax + bx;
            o.y = ay + by;
            ((float2*)out)[(size_t)n * 32 + hl] = o;
        }
    }
    __syncthreads();
    // overflow slow path (statistically never: CAP is mean + 11 sigma)
    int no = ovf_n;
    if (no > 0) {
        if (no > 128) no = 128;
        for (int i = w; i < no; i += 4) {
            unsigned u = ovf[i];
            int n = b * BROWS + (int)(u >> 17);
            if (n < N && half == 0) {
                unsigned uu = WTh[(size_t)(u & 0x1FFFFu) * 32 + hl];
                atomicAdd(&out[(size_t)n * 64 + 2 * hl],     bf_lo(uu));
                atomicAdd(&out[(size_t)n * 64 + 2 * hl + 1], bf_hi(uu));
            }
        }
    }
}

extern "C" void kernel_launch(void* const* d_in, const int* in_sizes, int n_in,
                              void* d_out, int out_size, void* d_ws, size_t ws_size,
                              hipStream_t stream) {
    const int*   edges = (const int*)d_in[0];    // [2, E]: rows then cols
    const float* W     = (const float*)d_in[1];  // [64, N]
    const float* bias  = (const float*)d_in[2];  // [64]
    float*       out   = (float*)d_out;          // [N, 64]

    const int E       = in_sizes[0] / 2;
    const int N       = in_sizes[1] / OUTC;
    const int NB      = (N + BROWS - 1) / BROWS;       // 1563
    const int nchunks = (E + CHUNK - 1) / CHUNK;       // 782
    const int ngroups = (nchunks + GRP - 1) / GRP;     // 25

    // workspace layout (~35.6 MB total)
    char* ws = (char*)d_ws;
    size_t off = 0;
    unsigned* WTh = (unsigned*)(ws + off); off += (size_t)N * 32 * sizeof(unsigned);
    off = (off + 255) & ~(size_t)255;
    int* hist = (int*)(ws + off);          off += (size_t)nchunks * NB * sizeof(int);
    off = (off + 255) & ~(size_t)255;
    int* cb = (int*)(ws + off);            off += (size_t)nchunks * NB * sizeof(int);
    off = (off + 255) & ~(size_t)255;
    int* gt = (int*)(ws + off);            off += (size_t)ngroups * NB * sizeof(int);
    off = (off + 255) & ~(size_t)255;
    int* base_g = (int*)(ws + off);        off += (size_t)(NB + 1) * sizeof(int);
    off = (off + 255) & ~(size_t)255;
    unsigned* packed = (unsigned*)(ws + off); off += (size_t)E * sizeof(unsigned);
    (void)ws_size;

    const int* rows = edges;
    const int* cols = edges + E;

    transpose_cast<<<(N + 63) / 64, 256, 0, stream>>>(W, WTh, N);
    count_chunks<<<nchunks, 256, 0, stream>>>(rows, hist, E, NB);
    scan_part<<<dim3(ngroups, (NB + 255) / 256), 256, 0, stream>>>(hist, cb, gt, NB, nchunks);
    scan_grp<<<(NB + 255) / 256, 256, 0, stream>>>(gt, base_g, NB, ngroups);
    scan_base<<<1, 512, 0, stream>>>(base_g, NB, E);
    scatter_chunks<<<nchunks, 256, 0, stream>>>(rows, cols, cb, gt, base_g, packed, E, NB);
    sort_gather<<<NB, 256, 0, stream>>>(WTh, packed, base_g, bias, out, N);
}